// Round 13
// baseline (239.722 us; speedup 1.0000x reference)
//
#include <hip/hip_runtime.h>
#include <hip/hip_bf16.h>

// EmbeddingRNN via MFMA, round 13 = R12 (122.5us) + deeper load-ahead at
// CONSTANT register cost + small byte cut.
//  (1) B-stream reshaped 2x8-frag -> 4x4-frag rotation (A4/B4/C4/D4, same 64
//      VGPRs): 3 clusters in flight -> ~180-200cy lookahead ~ L2 latency
//      (R12 analysis: ~100cy lookahead left waves vmcnt-stalled every kt).
//      All waits compiler-managed (per-register vmcnt) - no asm, no races.
//  (2) c-state -> fp16 in LDS (err +~4e-5, frees 16.4KB) -> kt1 nt0-3 also
//      LDS-resident (96KB). Global stream = kt1 nt4-7 + kt2-7 = 52 frags =
//      exactly 13 4-frag clusters. Bytes/step 488 -> 480KB.
//  (3) gather issued FIRST so compiler's acc-init wait is vmcnt(12) and the
//      preloaded clusters stay in flight.
// Gates: WRITE_SIZE == 8.2MB == out (spill-meter), FETCH < 6MB, VGPR <= 128.

#define DD      256
#define G4      1024
#define NCHAR   155
#define TSTEPS  16
#define RTILE   32
#define NROWS   8192
#define NBLOCKS (NROWS / RTILE)   // 256
#define NTHREADS 512              // 8 waves; wave w owns d-slice [w*32, w*32+32)

typedef __attribute__((ext_vector_type(8))) short bf16x8;
typedef __attribute__((ext_vector_type(8))) unsigned short u16x8;
typedef __attribute__((ext_vector_type(4))) float f32x4;

__device__ inline unsigned short f2bf_bits(float f) {
    __hip_bfloat16 h = __float2bfloat16(f);   // RTNE
    return *reinterpret_cast<unsigned short*>(&h);
}

__device__ inline float sigmoid_fast(float x) {
    return __builtin_amdgcn_rcpf(1.f + __expf(-x));
}

// ---------------- phase 0a: embWp8 = pack_bf16(emb @ W + b) ----------------
// value (char i, gate g, col d): w=d>>5, l15=d&15, nn=(d>>4)&1, nt=g*2+nn
// embWp8[ ((i*8 + w)*16 + l15)*8 + nt ]  (ushort bf16)
__global__ __launch_bounds__(256)
void embw_kernel(const float* __restrict__ emb, const float* __restrict__ W,
                 const float* __restrict__ b, unsigned short* __restrict__ embWp8) {
    const int i   = blockIdx.x;
    const int tid = threadIdx.x;
    float a0 = b[tid], a1 = b[256 + tid], a2 = b[512 + tid], a3 = b[768 + tid];
    const float* er = emb + i * DD;
    for (int k = 0; k < DD; ++k) {
        const float e = er[k];
        const float* wr = W + k * G4 + tid;
        a0 += e * wr[0];
        a1 += e * wr[256];
        a2 += e * wr[512];
        a3 += e * wr[768];
    }
    const int w = tid >> 5, l15 = tid & 15, nn = (tid >> 4) & 1;
    unsigned short* o = embWp8 + ((i * 8 + w) * 16 + l15) * 8 + nn;
    o[0] = f2bf_bits(a0); o[2] = f2bf_bits(a1);
    o[4] = f2bf_bits(a2); o[6] = f2bf_bits(a3);   // nt = g*2+nn
}

// ---------------- phase 0b: pack U into bf16 MFMA B-fragments ----------------
// up[((w*8 + kt)*8 + nt)*64 + lane]: lane l holds
//   U[kt*32+(l>>4)*8+j][g*256 + w*32 + nn*16 + (l&15)], nt=g*2+nn
__global__ __launch_bounds__(256)
void upack_kernel(const float* __restrict__ U, bf16x8* __restrict__ up) {
    const int gid  = blockIdx.x * 256 + threadIdx.x;   // 32768 total
    const int lane = gid & 63;
    const int nt   = (gid >> 6) & 7;
    const int kt   = (gid >> 9) & 7;
    const int w    = gid >> 12;
    const int g = nt >> 1, nn = nt & 1;
    const int col = g * 256 + w * 32 + nn * 16 + (lane & 15);
    const int k0  = kt * 32 + (lane >> 4) * 8;
    bf16x8 v;
#pragma unroll
    for (int j = 0; j < 8; ++j) v[j] = (short)f2bf_bits(U[(k0 + j) * G4 + col]);
    up[gid] = v;
}

// ---------------- phase 1: fused recurrence ----------------

// load one 4-frag cluster CI (global up tiles 12+4*CI .. 15+4*CI)
#define LOADC(DST, CI)                                                          \
    _Pragma("unroll")                                                           \
    for (int i4 = 0; i4 < 4; ++i4)                                              \
        (DST)[i4] = upw[(12 + 4 * (CI) + i4) * 64 + lane];

// set afr0/afr1 (A-fragments) for K-tile KT from swizzled bf16 h LDS
#define AFRSET(KT)                                                              \
    {                                                                           \
        const int kb = ((KT) * 32 + lg * 8) * 2;                                \
        const int r0 = l15, r1 = 16 + l15;                                      \
        afr0 = *(const bf16x8*)(rbb + ((r0 * 512 + kb) ^ ((r0 & 7) << 4)));     \
        afr1 = *(const bf16x8*)(rbb + ((r1 * 512 + kb) ^ ((r1 & 7) << 4)));     \
    }

// consume one 4-frag cluster into nt = HALF*4 .. HALF*4+3
#define CONS(BUF, HALF)                                                         \
    {                                                                           \
        _Pragma("unroll")                                                       \
        for (int q = 0; q < 4; ++q) {                                           \
            const int nt = (HALF) * 4 + q;                                      \
            acc[0][nt] = __builtin_amdgcn_mfma_f32_16x16x32_bf16(               \
                afr0, (BUF)[q], acc[0][nt], 0, 0, 0);                           \
            acc[1][nt] = __builtin_amdgcn_mfma_f32_16x16x32_bf16(               \
                afr1, (BUF)[q], acc[1][nt], 0, 0, 0);                           \
        }                                                                       \
    }

// kt=0 entirely from LDS-resident tile (8 nt)
#define KT0_LDS()                                                               \
    {                                                                           \
        const char* bp = (const char*)BresU + w * 8192 + lane * 16;             \
        _Pragma("unroll")                                                       \
        for (int nt = 0; nt < 8; ++nt) {                                        \
            bf16x8 bf = *(const bf16x8*)(bp + nt * 1024);                       \
            acc[0][nt] = __builtin_amdgcn_mfma_f32_16x16x32_bf16(               \
                afr0, bf, acc[0][nt], 0, 0, 0);                                 \
            acc[1][nt] = __builtin_amdgcn_mfma_f32_16x16x32_bf16(               \
                afr1, bf, acc[1][nt], 0, 0, 0);                                 \
        }                                                                       \
    }

// kt=1 nt0-3 from LDS-resident tile
#define KT1_LDS()                                                               \
    {                                                                           \
        const char* bp = (const char*)B1resU + w * 4096 + lane * 16;            \
        _Pragma("unroll")                                                       \
        for (int nt = 0; nt < 4; ++nt) {                                        \
            bf16x8 bf = *(const bf16x8*)(bp + nt * 1024);                       \
            acc[0][nt] = __builtin_amdgcn_mfma_f32_16x16x32_bf16(               \
                afr0, bf, acc[0][nt], 0, 0, 0);                                 \
            acc[1][nt] = __builtin_amdgcn_mfma_f32_16x16x32_bf16(               \
                afr1, bf, acc[1][nt], 0, 0, 0);                                 \
        }                                                                       \
    }

__global__ __launch_bounds__(NTHREADS)
void lstm_mfma(const int* __restrict__ x, const unsigned short* __restrict__ embWp8,
               const bf16x8* __restrict__ up, float* __restrict__ out) {
    // h: bf16 double buffer, byte-swizzle ^((row&7)<<4); c: fp16 stride 257.
    // BresU (kt0 full) + B1resU (kt1 nt0-3): step-invariant U, staged once.
    __shared__ __align__(16) unsigned short hb[2][RTILE * DD];       // 32768 B
    __shared__ unsigned short cb2[RTILE * 257];                      // 16448 B
    __shared__ int   xs[RTILE * TSTEPS];                             //  2048 B
    __shared__ __align__(16) unsigned short BresU[8 * 8 * 64 * 8];   // 65536 B
    __shared__ __align__(16) unsigned short B1resU[8 * 4 * 64 * 8];  // 32768 B

    const int tid  = threadIdx.x;
    const int w    = tid >> 6;
    const int lane = tid & 63;
    const int l15  = lane & 15, lg = lane >> 4;
    const int base = blockIdx.x * RTILE;

    xs[tid] = x[base * TSTEPS + tid];

    f32x4 acc[2][8];          // 64 accumulator regs (AGPR-side)

    // zero this thread's 16 c-slots (fp16)
#pragma unroll
    for (int mt = 0; mt < 2; ++mt)
#pragma unroll
        for (int nn = 0; nn < 2; ++nn)
#pragma unroll
            for (int j = 0; j < 4; ++j)
                cb2[(mt * 16 + lg * 4 + j) * 257 + w * 32 + nn * 16 + l15] = 0;

    const bf16x8* upw = up + w * 4096;    // this wave's 64KB packed U slice

    // ---- stage step-invariant U tiles into LDS (once) ----
    {
        char* bp = (char*)BresU + w * 8192 + lane * 16;
#pragma unroll
        for (int nt = 0; nt < 8; ++nt)
            *(bf16x8*)(bp + nt * 1024) = upw[nt * 64 + lane];         // kt=0
        char* b1 = (char*)B1resU + w * 4096 + lane * 16;
#pragma unroll
        for (int nt = 0; nt < 4; ++nt)
            *(bf16x8*)(b1 + nt * 1024) = upw[(8 + nt) * 64 + lane];   // kt=1 nt0-3
    }

    __syncthreads();

#pragma unroll 1
    for (int t = 0; t < TSTEPS; ++t) {
        // ---- (1) gather loads FIRST (oldest in vmcnt queue) ----
        u16x8 gv[2][4];
#pragma unroll
        for (int mt = 0; mt < 2; ++mt)
#pragma unroll
            for (int j = 0; j < 4; ++j) {
                const int r    = mt * 16 + lg * 4 + j;        // C/D row
                const int xrow = xs[r * TSTEPS + t];
                gv[mt][j] =
                    *(const u16x8*)(embWp8 + ((xrow * 8 + w) * 16 + l15) * 8);
            }

        bf16x8 A4[4], B4[4], C4[4], D4[4];
        bf16x8 afr0, afr1;
        if (t > 0) { LOADC(A4, 0) LOADC(B4, 1) LOADC(C4, 2) }  // 12 in flight

        // ---- (2) acc init from gather (compiler waits vmcnt(12): clusters live) ----
#pragma unroll
        for (int mt = 0; mt < 2; ++mt)
#pragma unroll
            for (int j = 0; j < 4; ++j)
#pragma unroll
                for (int gg = 0; gg < 8; ++gg)
                    acc[mt][gg][j] = __uint_as_float((unsigned)gv[mt][j][gg] << 16);

        // ---- (3) z += h @ U; kt0/kt1lo LDS-resident; 13-cluster 4-deep rotation ----
        if (t > 0) {
            const char* rbb = (const char*)hb[(t - 1) & 1];
            AFRSET(0) KT0_LDS()
            AFRSET(1) KT1_LDS()
            LOADC(D4, 3)   CONS(A4, 1)          // c0 = kt1 hi
            AFRSET(2) LOADC(A4, 4)  CONS(B4, 0) // c1 = kt2 lo
                      LOADC(B4, 5)  CONS(C4, 1) // c2 = kt2 hi
            AFRSET(3) LOADC(C4, 6)  CONS(D4, 0) // c3 = kt3 lo
                      LOADC(D4, 7)  CONS(A4, 1) // c4 = kt3 hi
            AFRSET(4) LOADC(A4, 8)  CONS(B4, 0) // c5 = kt4 lo
                      LOADC(B4, 9)  CONS(C4, 1) // c6 = kt4 hi
            AFRSET(5) LOADC(C4, 10) CONS(D4, 0) // c7 = kt5 lo
                      LOADC(D4, 11) CONS(A4, 1) // c8 = kt5 hi
            AFRSET(6) LOADC(A4, 12) CONS(B4, 0) // c9 = kt6 lo
                                    CONS(C4, 1) // c10 = kt6 hi
            AFRSET(7)               CONS(D4, 0) // c11 = kt7 lo
                                    CONS(A4, 1) // c12 = kt7 hi
        }

        // ---- gate update (Keras i,f,g,o; identity candidate/output) ----
        {
            char* wbb = (char*)hb[t & 1];
#pragma unroll
            for (int mt = 0; mt < 2; ++mt) {
#pragma unroll
                for (int nn = 0; nn < 2; ++nn) {
#pragma unroll
                    for (int j = 0; j < 4; ++j) {
                        const float zi = acc[mt][0 + nn][j];
                        const float zf = acc[mt][2 + nn][j];
                        const float zg = acc[mt][4 + nn][j];
                        const float zo = acc[mt][6 + nn][j];
                        const float ig = sigmoid_fast(zi);
                        const float fg = sigmoid_fast(zf);
                        const float og = sigmoid_fast(zo);
                        const int row = mt * 16 + lg * 4 + j;
                        const int d   = w * 32 + nn * 16 + l15;
                        _Float16* cp = (_Float16*)&cb2[row * 257 + d];
                        const float cn = fg * (float)(*cp) + ig * zg;
                        *cp = (_Float16)cn;
                        const float h = og * cn;
                        *(unsigned short*)(wbb +
                            ((row * 512 + d * 2) ^ ((row & 7) << 4))) = f2bf_bits(h);
                        if (t == TSTEPS - 1) out[(base + row) * DD + d] = h;
                    }
                }
            }
        }
        __syncthreads();   // publish h(t); prev-buffer reads done
    }
}

extern "C" void kernel_launch(void* const* d_in, const int* in_sizes, int n_in,
                              void* d_out, int out_size, void* d_ws, size_t ws_size,
                              hipStream_t stream) {
    const int*   x   = (const int*)d_in[0];
    const float* emb = (const float*)d_in[1];
    const float* W   = (const float*)d_in[2];
    const float* U   = (const float*)d_in[3];
    const float* b   = (const float*)d_in[4];
    float* out = (float*)d_out;

    unsigned short* embWp8 = (unsigned short*)d_ws;        // 317KB
    bf16x8*         up     = (bf16x8*)((char*)d_ws + (1 << 20));   // 512KB at +1MB

    embw_kernel<<<NCHAR, 256, 0, stream>>>(emb, W, b, embWp8);
    upack_kernel<<<128, 256, 0, stream>>>(U, up);
    lstm_mfma<<<NBLOCKS, NTHREADS, 0, stream>>>(x, embWp8, up, out);
}

// Round 14
// 113.394 us; speedup vs baseline: 2.1141x; 2.1141x over previous
//
#include <hip/hip_runtime.h>
#include <hip/hip_bf16.h>

// EmbeddingRNN via MFMA, round 14 = R12 chassis (122.5us, proven) + final byte
// cut. Evidence base: per-CU vector-load path tops out at ~22-26 B/cy/CU on
// every best-in-class gfx950 kernel (m97 22, m201 20, HK 24, hipBLASLt 25);
// R12 runs at 26.5 -> the only lever is fewer bytes through that path.
//  (1) c-state -> packed fp16 in REGISTERS (f16x16, 8 VGPR; precision
//      validated by R13's unchanged absmax). Frees 16.4KB LDS + 32 LDS ops.
//  (2) h single-buffered (frees 16KB) at +1 barrier/step.
//  (3) freed 32KB -> kt1 FULLY LDS-resident (kt0+kt1 = 128KB). Global stream
//      = kt2..7 + gather = 448KB/step (-6.7%).
// R13 lesson re-confirmed: no new persistent VGPR arrays (gv staging spilled).
// Gates: WRITE_SIZE == 8.2MB == out, FETCH < 6MB, VGPR <= 126.

#define DD      256
#define G4      1024
#define NCHAR   155
#define TSTEPS  16
#define RTILE   32
#define NROWS   8192
#define NBLOCKS (NROWS / RTILE)   // 256
#define NTHREADS 512              // 8 waves; wave w owns d-slice [w*32, w*32+32)

typedef __attribute__((ext_vector_type(8))) short bf16x8;
typedef __attribute__((ext_vector_type(8))) unsigned short u16x8;
typedef __attribute__((ext_vector_type(4))) float f32x4;
typedef __attribute__((ext_vector_type(16))) _Float16 f16x16;

__device__ inline unsigned short f2bf_bits(float f) {
    __hip_bfloat16 h = __float2bfloat16(f);   // RTNE
    return *reinterpret_cast<unsigned short*>(&h);
}

__device__ inline float sigmoid_fast(float x) {
    return __builtin_amdgcn_rcpf(1.f + __expf(-x));
}

// ---------------- phase 0a: embWp8 = pack_bf16(emb @ W + b) ----------------
// value (char i, gate g, col d): w=d>>5, l15=d&15, nn=(d>>4)&1, nt=g*2+nn
// embWp8[ ((i*8 + w)*16 + l15)*8 + nt ]  (ushort bf16)
__global__ __launch_bounds__(256)
void embw_kernel(const float* __restrict__ emb, const float* __restrict__ W,
                 const float* __restrict__ b, unsigned short* __restrict__ embWp8) {
    const int i   = blockIdx.x;
    const int tid = threadIdx.x;
    float a0 = b[tid], a1 = b[256 + tid], a2 = b[512 + tid], a3 = b[768 + tid];
    const float* er = emb + i * DD;
    for (int k = 0; k < DD; ++k) {
        const float e = er[k];
        const float* wr = W + k * G4 + tid;
        a0 += e * wr[0];
        a1 += e * wr[256];
        a2 += e * wr[512];
        a3 += e * wr[768];
    }
    const int w = tid >> 5, l15 = tid & 15, nn = (tid >> 4) & 1;
    unsigned short* o = embWp8 + ((i * 8 + w) * 16 + l15) * 8 + nn;
    o[0] = f2bf_bits(a0); o[2] = f2bf_bits(a1);
    o[4] = f2bf_bits(a2); o[6] = f2bf_bits(a3);   // nt = g*2+nn
}

// ---------------- phase 0b: pack U into bf16 MFMA B-fragments ----------------
// up[((w*8 + kt)*8 + nt)*64 + lane]: lane l holds
//   U[kt*32+(l>>4)*8+j][g*256 + w*32 + nn*16 + (l&15)], nt=g*2+nn
__global__ __launch_bounds__(256)
void upack_kernel(const float* __restrict__ U, bf16x8* __restrict__ up) {
    const int gid  = blockIdx.x * 256 + threadIdx.x;   // 32768 total
    const int lane = gid & 63;
    const int nt   = (gid >> 6) & 7;
    const int kt   = (gid >> 9) & 7;
    const int w    = gid >> 12;
    const int g = nt >> 1, nn = nt & 1;
    const int col = g * 256 + w * 32 + nn * 16 + (lane & 15);
    const int k0  = kt * 32 + (lane >> 4) * 8;
    bf16x8 v;
#pragma unroll
    for (int j = 0; j < 8; ++j) v[j] = (short)f2bf_bits(U[(k0 + j) * G4 + col]);
    up[gid] = v;
}

// ---------------- phase 1: fused recurrence ----------------

#define LOADB(DST, KT)                                                          \
    _Pragma("unroll")                                                           \
    for (int nt = 0; nt < 8; ++nt) (DST)[nt] = upw[((KT) * 8 + nt) * 64 + lane];

#define AFR_LOAD(KT)                                                            \
        const int kb = ((KT) * 32 + lg * 8) * 2;                                \
        const int r0 = l15, r1 = 16 + l15;                                      \
        bf16x8 afr0 = *(const bf16x8*)(rbb + ((r0 * 512 + kb) ^ ((r0 & 7) << 4))); \
        bf16x8 afr1 = *(const bf16x8*)(rbb + ((r1 * 512 + kb) ^ ((r1 & 7) << 4)));

// kt from global-loaded B regs
#define AFR_MFMA(KT, BARR)                                                      \
    {   AFR_LOAD(KT)                                                            \
        _Pragma("unroll")                                                       \
        for (int nt = 0; nt < 8; ++nt) {                                        \
            acc[0][nt] = __builtin_amdgcn_mfma_f32_16x16x32_bf16(               \
                afr0, (BARR)[nt], acc[0][nt], 0, 0, 0);                         \
            acc[1][nt] = __builtin_amdgcn_mfma_f32_16x16x32_bf16(               \
                afr1, (BARR)[nt], acc[1][nt], 0, 0, 0);                         \
        }                                                                       \
    }

// kt KT entirely from an LDS-resident tile (8 nt)
#define AFR_LDSRES(KT, BASE)                                                    \
    {   AFR_LOAD(KT)                                                            \
        const char* bp = (const char*)(BASE) + w * 8192 + lane * 16;            \
        _Pragma("unroll")                                                       \
        for (int nt = 0; nt < 8; ++nt) {                                        \
            bf16x8 bf = *(const bf16x8*)(bp + nt * 1024);                       \
            acc[0][nt] = __builtin_amdgcn_mfma_f32_16x16x32_bf16(               \
                afr0, bf, acc[0][nt], 0, 0, 0);                                 \
            acc[1][nt] = __builtin_amdgcn_mfma_f32_16x16x32_bf16(               \
                afr1, bf, acc[1][nt], 0, 0, 0);                                 \
        }                                                                       \
    }

__global__ __launch_bounds__(NTHREADS)
void lstm_mfma(const int* __restrict__ x, const unsigned short* __restrict__ embWp8,
               const bf16x8* __restrict__ up, float* __restrict__ out) {
    // h: bf16 SINGLE buffer, byte-swizzle ^((row&7)<<4); 2 barriers/step.
    // c: packed fp16 in registers (f16x16). BresU/B1resU: kt0+kt1 resident.
    __shared__ __align__(16) unsigned short hb[RTILE * DD];          // 16384 B
    __shared__ int xs[RTILE * TSTEPS];                               //  2048 B
    __shared__ __align__(16) unsigned short BresU[8 * 8 * 64 * 8];   // 65536 B
    __shared__ __align__(16) unsigned short B1resU[8 * 8 * 64 * 8];  // 65536 B

    const int tid  = threadIdx.x;
    const int w    = tid >> 6;
    const int lane = tid & 63;
    const int l15  = lane & 15, lg = lane >> 4;
    const int base = blockIdx.x * RTILE;

    xs[tid] = x[base * TSTEPS + tid];

    f32x4 acc[2][8];          // 64 accumulator regs
    f16x16 cst;               // 8 regs, packed fp16 cell state
#pragma unroll
    for (int i = 0; i < 16; ++i) cst[i] = (_Float16)0.f;

    const bf16x8* upw = up + w * 4096;    // this wave's 64KB packed U slice

    // ---- stage step-invariant U tiles into LDS (wave-private regions) ----
    {
        char* bp = (char*)BresU + w * 8192 + lane * 16;
#pragma unroll
        for (int nt = 0; nt < 8; ++nt)
            *(bf16x8*)(bp + nt * 1024) = upw[nt * 64 + lane];         // kt=0
        char* b1 = (char*)B1resU + w * 8192 + lane * 16;
#pragma unroll
        for (int nt = 0; nt < 8; ++nt)
            *(bf16x8*)(b1 + nt * 1024) = upw[(8 + nt) * 64 + lane];   // kt=1
    }

    __syncthreads();

#pragma unroll 1
    for (int t = 0; t < TSTEPS; ++t) {
        // ---- acc init: z = embW[x_t] gather (bf16, +b folded) ----
#pragma unroll
        for (int mt = 0; mt < 2; ++mt) {
#pragma unroll
            for (int j = 0; j < 4; ++j) {
                const int r    = mt * 16 + lg * 4 + j;        // C/D row
                const int xrow = xs[r * TSTEPS + t];
                const u16x8 u =
                    *(const u16x8*)(embWp8 + ((xrow * 8 + w) * 16 + l15) * 8);
#pragma unroll
                for (int gg = 0; gg < 8; ++gg)
                    acc[mt][gg][j] = __uint_as_float((unsigned)u[gg] << 16);
            }
        }

        // ---- z += h @ U; kt0+kt1 LDS-resident; kt2..7 2-deep reg pipeline ----
        if (t > 0) {
            const char* rbb = (const char*)hb;
            bf16x8 bA[8], bB[8];
            LOADB(bA, 2) LOADB(bB, 3)         // 16 loads fly under 32 LDS MFMAs
            AFR_LDSRES(0, BresU)              // kt0: LDS only, starts instantly
            AFR_LDSRES(1, B1resU)             // kt1: LDS only
#pragma unroll 1
            for (int ktp = 0; ktp < 3; ++ktp) {
                const int kta = 2 * ktp + 2, ktb = kta + 1;   // (2,3)(4,5)(6,7)
                AFR_MFMA(kta, bA)
                if (ktp < 2) { LOADB(bA, kta + 2) }
                AFR_MFMA(ktb, bB)
                if (ktp < 2) { LOADB(bB, ktb + 2) }
            }
        }

        __syncthreads();   // #1: all reads of h(t-1) complete before overwrite

        // ---- gate update (Keras i,f,g,o; identity candidate/output) ----
        {
            char* wbb = (char*)hb;
#pragma unroll
            for (int mt = 0; mt < 2; ++mt) {
#pragma unroll
                for (int nn = 0; nn < 2; ++nn) {
#pragma unroll
                    for (int j = 0; j < 4; ++j) {
                        const float zi = acc[mt][0 + nn][j];
                        const float zf = acc[mt][2 + nn][j];
                        const float zg = acc[mt][4 + nn][j];
                        const float zo = acc[mt][6 + nn][j];
                        const float ig = sigmoid_fast(zi);
                        const float fg = sigmoid_fast(zf);
                        const float og = sigmoid_fast(zo);
                        const int ci = mt * 8 + nn * 4 + j;
                        const float cn = fg * (float)cst[ci] + ig * zg;
                        cst[ci] = (_Float16)cn;
                        const float h = og * cn;
                        const int row = mt * 16 + lg * 4 + j;
                        const int d   = w * 32 + nn * 16 + l15;
                        *(unsigned short*)(wbb +
                            ((row * 512 + d * 2) ^ ((row & 7) << 4))) = f2bf_bits(h);
                        if (t == TSTEPS - 1) out[(base + row) * DD + d] = h;
                    }
                }
            }
        }
        __syncthreads();   // #2: h(t) visible for next step's A-reads
    }
}

extern "C" void kernel_launch(void* const* d_in, const int* in_sizes, int n_in,
                              void* d_out, int out_size, void* d_ws, size_t ws_size,
                              hipStream_t stream) {
    const int*   x   = (const int*)d_in[0];
    const float* emb = (const float*)d_in[1];
    const float* W   = (const float*)d_in[2];
    const float* U   = (const float*)d_in[3];
    const float* b   = (const float*)d_in[4];
    float* out = (float*)d_out;

    unsigned short* embWp8 = (unsigned short*)d_ws;        // 317KB
    bf16x8*         up     = (bf16x8*)((char*)d_ws + (1 << 20));   // 512KB at +1MB

    embw_kernel<<<NCHAR, 256, 0, stream>>>(emb, W, b, embWp8);
    upack_kernel<<<128, 256, 0, stream>>>(U, up);
    lstm_mfma<<<NBLOCKS, NTHREADS, 0, stream>>>(x, embWp8, up, out);
}